// Round 9
// baseline (502.434 us; speedup 1.0000x reference)
//
#include <hip/hip_runtime.h>
#include <hip/hip_bf16.h>

// Fused 2-layer LSTM (H=64) + Dense(64,sigmoid) + Dense(1,sigmoid), MFMA bf16.
// Round-5 split-wave structure (213us champion) + 2 pipe cuts:
//  (1) 8-transcendental cell (fused rcp for i*tanh(g) and o*tanh(c)), c clamped
//  (2) x never touches LDS: per-lane global prefetch one window ahead into a
//      register B-frag (L1-resident; first MFMA issues with no lgkmcnt wait)
// B=4096, T=256, F=32. WG = 1024 thr = 16 waves, BB=16 rows, grid 256.
// Waves 0-7: layer 1 step u (2 tiles, 6 MFMA). Waves 8-15: layer 2 step u-1
// (2 tiles, 8 MFMA). One barrier per window. h1/h2 double-buffered bf16 in LDS
// (row stride 72 shorts). Transposed-z: tile rows = unit_local*4+gate, so lane
// (n,q) owns all 4 gates of cell (batch n, unit 4T+q). Scales folded into
// weights (i,f,o: -log2e; g: +2log2e); cell state pre-scaled by 2log2e; bias
// rides in the MFMA C operand. ALL bf16 packs RNE (round-6 lesson: biased
// rounding integrates over 256 steps). NO __shfl in the hot loop (round-8
// lesson: shfl = ds_* op, adds LDS-pipe traffic).
// MFMA 16x16x32 layouts (learn_hip-verified):
//   A[m=lane&15][k=(lane>>4)*8+j], B[k=(lane>>4)*8+j][n=lane&15],
//   C/D: col=lane&15, row=(lane>>4)*4+reg.

typedef __attribute__((ext_vector_type(8))) short short8;
typedef __attribute__((ext_vector_type(4))) float floatx4;
typedef __attribute__((ext_vector_type(4))) int   intx4;

__device__ __forceinline__ float ex2(float x){ return __builtin_amdgcn_exp2f(x); }
__device__ __forceinline__ float rcp_(float x){ return __builtin_amdgcn_rcpf(x); }
__device__ __forceinline__ float sigm(float x){ return rcp_(1.0f + ex2(-1.44269504f*x)); }
__device__ __forceinline__ unsigned bfbits(float f){       // RNE f32->bf16 (raw bits)
    unsigned u = __builtin_bit_cast(unsigned, f);
    u += 0x7FFFu + ((u >> 16) & 1u);
    return u >> 16;
}
__device__ __forceinline__ short f2bf(float f){ return (short)bfbits(f); }
__device__ __forceinline__ unsigned pack_bf2(float a, float b){  // RNE pk
    float2 t; t.x = a; t.y = b;
    __hip_bfloat162 p = __float22bfloat162_rn(t);
    unsigned r; __builtin_memcpy(&r, &p, 4);
    return r;
}
__device__ __forceinline__ short8 cvt8(const floatx4& a, const floatx4& b){
    intx4 p;
    p[0] = (int)pack_bf2(a[0], a[1]);
    p[1] = (int)pack_bf2(a[2], a[3]);
    p[2] = (int)pack_bf2(b[0], b[1]);
    p[3] = (int)pack_bf2(b[2], b[3]);
    return __builtin_bit_cast(short8, p);
}

#define MFMA_BF16 __builtin_amdgcn_mfma_f32_16x16x32_bf16

// 8-trans cell: z=(i,f,g,o) pre-scaled (i,f,o by -LG; g by 2LG); c scaled 2LG.
// i*tanh(zg) = (e2-1)/((1+e0)(1+e2));  o*tanh(c) = (ec-1)/((1+e3)(1+ec)).
__device__ __forceinline__ float cellh(const floatx4& z, float& c){
    float e0 = ex2(z[0]);
    float e1 = ex2(z[1]);
    float e2 = ex2(z[2]);
    float e3 = ex2(z[3]);
    float fr = rcp_(1.0f + e1);                       // f gate
    float pr = rcp_((1.0f + e0) * (1.0f + e2));
    float ig = (e2 - 1.0f) * pr;                      // i * tanh(zg)
    c = fmaf(fr, c, 2.88539008f * ig);                // c (scaled 2LG)
    c = fminf(fmaxf(c, -80.0f), 80.0f);               // guard ec overflow
    float ec = ex2(c);
    float hr = rcp_((1.0f + e3) * (1.0f + ec));
    return (ec - 1.0f) * hr;                          // o * tanh(c)
}

__global__ __launch_bounds__(1024, 1)
void lstm2_tz3(const float* __restrict__ x,
               const float* __restrict__ W1, const float* __restrict__ U1, const float* __restrict__ b1,
               const float* __restrict__ W2, const float* __restrict__ U2, const float* __restrict__ b2,
               const float* __restrict__ Wd, const float* __restrict__ bd,
               const float* __restrict__ Wo, const float* __restrict__ bo,
               float* __restrict__ out)
{
    __shared__ __align__(16) short h1s[2 * 1152];   // [par][batch*72 + unit]
    __shared__ __align__(16) short h2s[2 * 1152];
    __shared__ float psum[4][16];

    const int tid  = threadIdx.x;
    const int w    = tid >> 6;            // 0..15
    const bool isL1 = (w < 8);
    const int wv   = isL1 ? w : (w - 8);  // 0..7 within group
    const int lane = tid & 63;
    const int n    = lane & 15;           // batch row (B-col); also A-frag m
    const int q    = lane >> 4;           // quad
    const int b0   = blockIdx.x * 16;

    const float LG = 1.44269504f;         // log2(e)

    // A-frag row role: m=n -> (unit_local = n>>2, gate = n&3)
    const int ugl = n >> 2;
    const int gA  = n & 3;
    const float sA = (gA == 2) ? (2.0f * LG) : (-LG);

    // ---- one-time: weight A-fragments + bias C vectors ----
    short8  Wa[8];
    floatx4 bC[2];
    if (isL1) {
#pragma unroll
        for (int tt = 0; tt < 2; ++tt) {
            const int t = wv * 2 + tt;
            const int ncol = gA * 64 + t * 4 + ugl;
#pragma unroll
            for (int j = 0; j < 8; ++j) {
                const int k = q * 8 + j;
                Wa[tt * 3 + 0][j] = f2bf(W1[k * 256 + ncol] * sA);
                Wa[tt * 3 + 1][j] = f2bf(U1[k * 256 + ncol] * sA);
                Wa[tt * 3 + 2][j] = f2bf(U1[(32 + k) * 256 + ncol] * sA);
            }
#pragma unroll
            for (int r = 0; r < 4; ++r)
                bC[tt][r] = b1[r * 64 + t * 4 + q] * ((r == 2) ? (2.0f * LG) : (-LG));
        }
    } else {
#pragma unroll
        for (int tt = 0; tt < 2; ++tt) {
            const int t = wv * 2 + tt;
            const int ncol = gA * 64 + t * 4 + ugl;
#pragma unroll
            for (int j = 0; j < 8; ++j) {
                const int k = q * 8 + j;
                Wa[tt * 4 + 0][j] = f2bf(W2[k * 256 + ncol] * sA);
                Wa[tt * 4 + 1][j] = f2bf(W2[(32 + k) * 256 + ncol] * sA);
                Wa[tt * 4 + 2][j] = f2bf(U2[k * 256 + ncol] * sA);
                Wa[tt * 4 + 3][j] = f2bf(U2[(32 + k) * 256 + ncol] * sA);
            }
#pragma unroll
            for (int r = 0; r < 4; ++r)
                bC[tt][r] = b2[r * 64 + t * 4 + q] * ((r == 2) ? (2.0f * LG) : (-LG));
        }
    }

    // ---- zero h double-buffers ----
    {
        unsigned* p1 = (unsigned*)&h1s[0];
        unsigned* p2 = (unsigned*)&h2s[0];
        for (int i = tid; i < 1152; i += 1024) { p1[i] = 0u; p2[i] = 0u; }
    }

    // ---- x: per-lane global prefetch (L1 lanes only) ----
    // lane (n,q) owns B-frag elements x[b0+n][t][q*8 .. q*8+7]
    const float* xlane = x + (size_t)(b0 + n) * 8192 + q * 8;   // T*F = 8192
    floatx4 xlo, xhi;      // fp32 of next step's x
    short8  bx;            // bf16 frag of current step's x
    if (isL1) {
        xlo = *(const floatx4*)(xlane);          // x[0]
        xhi = *(const floatx4*)(xlane + 4);
    }
    __syncthreads();
    if (isL1) {
        bx  = cvt8(xlo, xhi);                    // frag for step 0
        xlo = *(const floatx4*)(xlane + 32);     // prefetch x[1]
        xhi = *(const floatx4*)(xlane + 36);
    }

    // lane-invariant LDS sub-addresses
    const int rdA = n * 72 + q * 8;        // h frag lo
    const int rdB = rdA + 32;              // h frag hi

    float c[2] = {0, 0};                   // cell state, pre-scaled by 2*log2e

    for (int u = 0; u <= 256; ++u) {
        const int par = u & 1, pax = par ^ 1;
        if (isL1) {
            if (u < 256) {
                // ---- layer 1, step u: z^T = Wt @ [x_u | h1_{u-1}]^T ----
                short8 h1a = *(const short8*)&h1s[pax * 1152 + rdA];
                short8 h1c = *(const short8*)&h1s[pax * 1152 + rdB];
#pragma unroll
                for (int tt = 0; tt < 2; ++tt) {
                    floatx4 z = bC[tt];
                    z = MFMA_BF16(Wa[tt * 3 + 0], bx,  z, 0, 0, 0); // reg-ready
                    z = MFMA_BF16(Wa[tt * 3 + 1], h1a, z, 0, 0, 0);
                    z = MFMA_BF16(Wa[tt * 3 + 2], h1c, z, 0, 0, 0);
                    float hv = cellh(z, c[tt]);
                    h1s[par * 1152 + n * 72 + (wv * 2 + tt) * 4 + q] = f2bf(hv);
                }
                // convert next frag; prefetch the one after
                if (u < 255) {
                    bx = cvt8(xlo, xhi);
                    if (u < 254) {
                        xlo = *(const floatx4*)(xlane + (size_t)(u + 2) * 32);
                        xhi = *(const floatx4*)(xlane + (size_t)(u + 2) * 32 + 4);
                    }
                }
            }
        } else {
            if (u >= 1) {
                // ---- layer 2, step t=u-1: z^T = Wt @ [h1_t | h2_{t-1}]^T ----
                short8 bh0 = *(const short8*)&h1s[pax * 1152 + rdA];
                short8 bh1 = *(const short8*)&h1s[pax * 1152 + rdB];
                short8 bg0 = *(const short8*)&h2s[par * 1152 + rdA];
                short8 bg1 = *(const short8*)&h2s[par * 1152 + rdB];
#pragma unroll
                for (int tt = 0; tt < 2; ++tt) {
                    floatx4 z = bC[tt];
                    z = MFMA_BF16(Wa[tt * 4 + 0], bh0, z, 0, 0, 0);
                    z = MFMA_BF16(Wa[tt * 4 + 1], bh1, z, 0, 0, 0);
                    z = MFMA_BF16(Wa[tt * 4 + 2], bg0, z, 0, 0, 0);
                    z = MFMA_BF16(Wa[tt * 4 + 3], bg1, z, 0, 0, 0);
                    float hv = cellh(z, c[tt]);
                    h2s[pax * 1152 + n * 72 + (wv * 2 + tt) * 4 + q] = f2bf(hv);
                }
            }
        }
        __syncthreads();
    }

    // ---- epilogue (waves 8-11): h_last = h2[255] in h2s[1152..] ----
    if (!isL1 && wv < 4) {
        const int colD = wv * 16 + n;
        short8 wd0, wd1;
#pragma unroll
        for (int j = 0; j < 8; ++j) {
            wd0[j] = f2bf(Wd[(q * 8 + j) * 64 + colD] * (-LG));
            wd1[j] = f2bf(Wd[(32 + q * 8 + j) * 64 + colD] * (-LG));
        }
        short8 hA0 = *(const short8*)&h2s[1152 + rdA];
        short8 hA1 = *(const short8*)&h2s[1152 + rdB];
        const float bdv = bd[colD] * (-LG);
        floatx4 dacc = { bdv, bdv, bdv, bdv };
        dacc = MFMA_BF16(hA0, wd0, dacc, 0, 0, 0);
        dacc = MFMA_BF16(hA1, wd1, dacc, 0, 0, 0);
        const float wo = Wo[colD];
#pragma unroll
        for (int r = 0; r < 4; ++r) {
            float p = rcp_(1.0f + ex2(dacc[r])) * wo;   // sigm (scale folded)
            p += __shfl_xor(p, 1, 64);
            p += __shfl_xor(p, 2, 64);
            p += __shfl_xor(p, 4, 64);
            p += __shfl_xor(p, 8, 64);                  // sum over 16 dense units
            if (n == 0) psum[wv][q * 4 + r] = p;
        }
    }
    __syncthreads();
    if (tid < 16) {
        float s = psum[0][tid] + psum[1][tid] + psum[2][tid] + psum[3][tid] + bo[0];
        out[b0 + tid] = sigm(s);
    }
}

extern "C" void kernel_launch(void* const* d_in, const int* in_sizes, int n_in,
                              void* d_out, int out_size, void* d_ws, size_t ws_size,
                              hipStream_t stream) {
    (void)in_sizes; (void)n_in; (void)d_ws; (void)ws_size; (void)out_size;
    const float* x  = (const float*)d_in[0];
    const float* W1 = (const float*)d_in[1];
    const float* U1 = (const float*)d_in[2];
    const float* b1 = (const float*)d_in[3];
    const float* W2 = (const float*)d_in[4];
    const float* U2 = (const float*)d_in[5];
    const float* b2 = (const float*)d_in[6];
    const float* Wd = (const float*)d_in[7];
    const float* bd = (const float*)d_in[8];
    const float* Wo = (const float*)d_in[9];
    const float* bo = (const float*)d_in[10];
    lstm2_tz3<<<dim3(256), dim3(1024), 0, stream>>>(
        x, W1, U1, b1, W2, U2, b2, Wd, bd, Wo, bo, (float*)d_out);
}

// Round 10
// 343.764 us; speedup vs baseline: 1.4616x; 1.4616x over previous
//
#include <hip/hip_runtime.h>

// Fused 2-layer LSTM (H=64) + Dense(64,sigmoid) + Dense(1,sigmoid), MFMA bf16.
// EXACT round-5 structure (213us champion) with ONE change: 8-transcendental
// fused cell (was 10): i*tanh(g) and o*tanh(c) each share a single rcp.
// B=4096, T=256, F=32. WG = 1024 threads = 16 waves, BB=16 rows, grid 256.
// Waves 0-7: layer 1 step u (2 tiles, 6 MFMA). Waves 8-15: layer 2 step u-1
// (2 tiles, 8 MFMA). One barrier per window. h1/h2/x double-buffered bf16 in
// LDS (row stride 72 shorts). Transposed-z: tile rows = unit_local*4 + gate,
// lane (n,q) owns all 4 gates of cell (batch n, unit 4T+q). Scales folded into
// weights (i,f,o: -log2e; g: +2log2e); cell state pre-scaled by 2log2e; bias
// rides in the MFMA C operand. ALL bf16 packs RNE (r6 lesson: biased rounding
// integrates over 256 steps). No __shfl in hot loop (r8: shfl = ds_ op).
// x staged by tid<256 coalesced loads (r9 lesson: per-lane global x = 16
// cache lines per instruction, VMEM-pipe serialization).
// MFMA 16x16x32 layouts (learn_hip-verified):
//   A[m=lane&15][k=(lane>>4)*8+j], B[k=(lane>>4)*8+j][n=lane&15],
//   C/D: col=lane&15, row=(lane>>4)*4+reg.

typedef __attribute__((ext_vector_type(8))) short short8;
typedef __attribute__((ext_vector_type(4))) float floatx4;
typedef __attribute__((ext_vector_type(2))) float floatx2;

__device__ __forceinline__ float ex2(float x){ return __builtin_amdgcn_exp2f(x); }
__device__ __forceinline__ float rcp_(float x){ return __builtin_amdgcn_rcpf(x); }
__device__ __forceinline__ float sigm(float x){ return rcp_(1.0f + ex2(-1.44269504f*x)); }
__device__ __forceinline__ unsigned bfbits(float f){       // RNE f32->bf16 (raw bits)
    unsigned u = __builtin_bit_cast(unsigned, f);
    u += 0x7FFFu + ((u >> 16) & 1u);
    return u >> 16;
}
__device__ __forceinline__ short f2bf(float f){ return (short)bfbits(f); }
__device__ __forceinline__ unsigned pack_bf2(float a, float b){
    return bfbits(a) | (bfbits(b) << 16);
}

#define MFMA_BF16 __builtin_amdgcn_mfma_f32_16x16x32_bf16

// 8-trans cell: z=(i,f,g,o) pre-scaled (i,f,o by -LG; g by 2LG); c scaled 2LG.
// i*tanh(zg) = (e2-1)/((1+e0)(1+e2));  o*tanh(c) = (ec-1)/((1+e3)(1+ec)).
__device__ __forceinline__ float cellh(const floatx4& z, float& c){
    float e0 = ex2(z[0]);
    float e1 = ex2(z[1]);
    float e2 = ex2(z[2]);
    float e3 = ex2(z[3]);
    float fr = rcp_(1.0f + e1);                       // f gate
    float pr = rcp_((1.0f + e0) * (1.0f + e2));
    float ig = (e2 - 1.0f) * pr;                      // i * tanh(zg)
    c = fmaf(fr, c, 2.88539008f * ig);                // c (scaled 2LG)
    c = fminf(fmaxf(c, -80.0f), 80.0f);               // guard 2^c overflow
    float ec = ex2(c);
    float hr = rcp_((1.0f + e3) * (1.0f + ec));
    return (ec - 1.0f) * hr;                          // o * tanh(c)
}

__global__ __launch_bounds__(1024, 1)
void lstm2_tz4(const float* __restrict__ x,
               const float* __restrict__ W1, const float* __restrict__ U1, const float* __restrict__ b1,
               const float* __restrict__ W2, const float* __restrict__ U2, const float* __restrict__ b2,
               const float* __restrict__ Wd, const float* __restrict__ bd,
               const float* __restrict__ Wo, const float* __restrict__ bo,
               float* __restrict__ out)
{
    __shared__ __align__(16) short h1b[2][16 * 72];   // [buf][batch*72 + unit]
    __shared__ __align__(16) short h2b[2][16 * 72];
    __shared__ __align__(16) short xsb[2][16 * 40];   // [buf][batch*40 + feat]
    __shared__ float psum[4][16];

    const int tid  = threadIdx.x;
    const int w    = tid >> 6;            // 0..15
    const bool isL1 = (w < 8);
    const int wv   = isL1 ? w : (w - 8);  // 0..7 within group
    const int lane = tid & 63;
    const int n    = lane & 15;           // batch row (B-col); also A-frag m
    const int q    = lane >> 4;           // quad
    const int b0   = blockIdx.x * 16;

    const float LG = 1.44269504f;         // log2(e)

    // A-frag row role: m=n -> (unit_local = n>>2, gate = n&3)
    const int ugl = n >> 2;
    const int gA  = n & 3;
    const float sA = (gA == 2) ? (2.0f * LG) : (-LG);

    // ---- one-time: weight A-fragments + bias C vectors ----
    short8  Wa[8];
    floatx4 bC[2];
    if (isL1) {
#pragma unroll
        for (int tt = 0; tt < 2; ++tt) {
            const int t = wv * 2 + tt;
            const int ncol = gA * 64 + t * 4 + ugl;
#pragma unroll
            for (int j = 0; j < 8; ++j) {
                const int k = q * 8 + j;
                Wa[tt * 3 + 0][j] = f2bf(W1[k * 256 + ncol] * sA);
                Wa[tt * 3 + 1][j] = f2bf(U1[k * 256 + ncol] * sA);
                Wa[tt * 3 + 2][j] = f2bf(U1[(32 + k) * 256 + ncol] * sA);
            }
#pragma unroll
            for (int r = 0; r < 4; ++r)
                bC[tt][r] = b1[r * 64 + t * 4 + q] * ((r == 2) ? (2.0f * LG) : (-LG));
        }
    } else {
#pragma unroll
        for (int tt = 0; tt < 2; ++tt) {
            const int t = wv * 2 + tt;
            const int ncol = gA * 64 + t * 4 + ugl;
#pragma unroll
            for (int j = 0; j < 8; ++j) {
                const int k = q * 8 + j;
                Wa[tt * 4 + 0][j] = f2bf(W2[k * 256 + ncol] * sA);
                Wa[tt * 4 + 1][j] = f2bf(W2[(32 + k) * 256 + ncol] * sA);
                Wa[tt * 4 + 2][j] = f2bf(U2[k * 256 + ncol] * sA);
                Wa[tt * 4 + 3][j] = f2bf(U2[(32 + k) * 256 + ncol] * sA);
            }
#pragma unroll
            for (int r = 0; r < 4; ++r)
                bC[tt][r] = b2[r * 64 + t * 4 + q] * ((r == 2) ? (2.0f * LG) : (-LG));
        }
    }

    // ---- zero h double-buffers ----
    {
        unsigned* p1 = (unsigned*)&h1b[0][0];
        unsigned* p2 = (unsigned*)&h2b[0][0];
        for (int i = tid; i < 1152; i += 1024) { p1[i] = 0u; p2[i] = 0u; }
    }

    // ---- x staging (tid<256): 2 fp32 of batch row (tid>>4) per step ----
    const int xr = tid >> 4;
    const int xc = (tid & 15) * 2;
    const float* xrow = x + (size_t)(b0 + xr) * 8192 + xc;   // T*F = 8192
    floatx2 xv0;
    if (tid < 256) {
        floatx2 v = *(const floatx2*)xrow;                    // x[0]
        *(unsigned*)&xsb[0][xr * 40 + xc] = pack_bf2(v.x, v.y);
        xv0 = *(const floatx2*)(xrow + 32);                   // x[1]
    }
    __syncthreads();

    // lane-invariant LDS sub-addresses
    const int rdA = n * 72 + q * 8;        // h frag lo
    const int rdB = rdA + 32;              // h frag hi
    const int rdX = n * 40 + q * 8;        // x frag

    float c[2] = {0, 0};                   // cell state, pre-scaled by 2*log2e

    for (int u = 0; u <= 256; ++u) {
        const int par = u & 1, pax = par ^ 1;
        if (isL1) {
            if (u < 256) {
                // ---- layer 1, step u: z^T = Wt @ [x_u | h1_{u-1}]^T ----
                short8 bx  = *(const short8*)&xsb[par][rdX];
                short8 h1a = *(const short8*)&h1b[pax][rdA];
                short8 h1c = *(const short8*)&h1b[pax][rdB];
#pragma unroll
                for (int tt = 0; tt < 2; ++tt) {
                    floatx4 z = bC[tt];
                    z = MFMA_BF16(Wa[tt * 3 + 0], bx,  z, 0, 0, 0);
                    z = MFMA_BF16(Wa[tt * 3 + 1], h1a, z, 0, 0, 0);
                    z = MFMA_BF16(Wa[tt * 3 + 2], h1c, z, 0, 0, 0);
                    float hv = cellh(z, c[tt]);
                    h1b[par][n * 72 + (wv * 2 + tt) * 4 + q] = f2bf(hv);
                }
                // stage x[u+1] into other buffer; prefetch x[u+2]
                if (tid < 256 && u < 255) {
                    *(unsigned*)&xsb[pax][xr * 40 + xc] = pack_bf2(xv0.x, xv0.y);
                    if (u < 254) xv0 = *(const floatx2*)(xrow + (size_t)(u + 2) * 32);
                }
            }
        } else {
            if (u >= 1) {
                // ---- layer 2, step t=u-1: z^T = Wt @ [h1_t | h2_{t-1}]^T ----
                short8 bh0 = *(const short8*)&h1b[pax][rdA];
                short8 bh1 = *(const short8*)&h1b[pax][rdB];
                short8 bg0 = *(const short8*)&h2b[par][rdA];
                short8 bg1 = *(const short8*)&h2b[par][rdB];
#pragma unroll
                for (int tt = 0; tt < 2; ++tt) {
                    floatx4 z = bC[tt];
                    z = MFMA_BF16(Wa[tt * 4 + 0], bh0, z, 0, 0, 0);
                    z = MFMA_BF16(Wa[tt * 4 + 1], bh1, z, 0, 0, 0);
                    z = MFMA_BF16(Wa[tt * 4 + 2], bg0, z, 0, 0, 0);
                    z = MFMA_BF16(Wa[tt * 4 + 3], bg1, z, 0, 0, 0);
                    float hv = cellh(z, c[tt]);
                    h2b[pax][n * 72 + (wv * 2 + tt) * 4 + q] = f2bf(hv);
                }
            }
        }
        __syncthreads();
    }

    // ---- epilogue (waves 8-11): h_last = h2[255] in h2b[1] ----
    if (!isL1 && wv < 4) {
        const int colD = wv * 16 + n;
        short8 wd0, wd1;
#pragma unroll
        for (int j = 0; j < 8; ++j) {
            wd0[j] = f2bf(Wd[(q * 8 + j) * 64 + colD] * (-LG));
            wd1[j] = f2bf(Wd[(32 + q * 8 + j) * 64 + colD] * (-LG));
        }
        short8 hA0 = *(const short8*)&h2b[1][rdA];
        short8 hA1 = *(const short8*)&h2b[1][rdB];
        const float bdv = bd[colD] * (-LG);
        floatx4 dacc = { bdv, bdv, bdv, bdv };
        dacc = MFMA_BF16(hA0, wd0, dacc, 0, 0, 0);
        dacc = MFMA_BF16(hA1, wd1, dacc, 0, 0, 0);
        const float wo = Wo[colD];
#pragma unroll
        for (int r = 0; r < 4; ++r) {
            float p = rcp_(1.0f + ex2(dacc[r])) * wo;   // sigm (scale folded)
            p += __shfl_xor(p, 1, 64);
            p += __shfl_xor(p, 2, 64);
            p += __shfl_xor(p, 4, 64);
            p += __shfl_xor(p, 8, 64);                  // sum over 16 dense units
            if (n == 0) psum[wv][q * 4 + r] = p;
        }
    }
    __syncthreads();
    if (tid < 16) {
        float s = psum[0][tid] + psum[1][tid] + psum[2][tid] + psum[3][tid] + bo[0];
        out[b0 + tid] = sigm(s);
    }
}

extern "C" void kernel_launch(void* const* d_in, const int* in_sizes, int n_in,
                              void* d_out, int out_size, void* d_ws, size_t ws_size,
                              hipStream_t stream) {
    (void)in_sizes; (void)n_in; (void)d_ws; (void)ws_size; (void)out_size;
    const float* x  = (const float*)d_in[0];
    const float* W1 = (const float*)d_in[1];
    const float* U1 = (const float*)d_in[2];
    const float* b1 = (const float*)d_in[3];
    const float* W2 = (const float*)d_in[4];
    const float* U2 = (const float*)d_in[5];
    const float* b2 = (const float*)d_in[6];
    const float* Wd = (const float*)d_in[7];
    const float* bd = (const float*)d_in[8];
    const float* Wo = (const float*)d_in[9];
    const float* bo = (const float*)d_in[10];
    lstm2_tz4<<<dim3(256), dim3(1024), 0, stream>>>(
        x, W1, U1, b1, W2, U2, b2, Wd, bd, Wo, bo, (float*)d_out);
}